// Round 7
// baseline (308.211 us; speedup 1.0000x reference)
//
#include <hip/hip_runtime.h>
#include <stdint.h>

// x: (8,128,16,16) f32 ; codebook: (4,4096,32) f32 ; temperature: (4,1,1,1)
// row = (n*4+m)*256 + hw, 8192 rows, K=4096, D=32
// outputs (flat f32): sample[33554432] code[8192] one_hot[33554432] logit[33554432]

__device__ __forceinline__ uint32_t rotl32(uint32_t x, uint32_t r){
  return (x << r) | (x >> (32u - r));
}

// JAX threefry2x32, key (0,42), partitionable scheme: bits = o0^o1 of
// threefry((0,42),(0,e)); u = bitcast((bits>>9)|0x3F800000)-1, clip, g=-log(-log(u)).
// VALIDATED bit-exact vs reference (Rounds 2,4,6) — do not modify.
__device__ __forceinline__ float gumbel_from_e(uint32_t e){
  uint32_t x0 = 0u, x1 = e;
  const uint32_t ks0 = 0u, ks1 = 42u, ks2 = 0x1BD11BF0u;
  x0 += ks0; x1 += ks1;
#define TFR4(a,b,c,d2) \
  x0 += x1; x1 = rotl32(x1,(a)); x1 ^= x0; \
  x0 += x1; x1 = rotl32(x1,(b)); x1 ^= x0; \
  x0 += x1; x1 = rotl32(x1,(c)); x1 ^= x0; \
  x0 += x1; x1 = rotl32(x1,(d2)); x1 ^= x0;
  TFR4(13,15,26,6)  x0 += ks1; x1 += ks2 + 1u;
  TFR4(17,29,16,24) x0 += ks2; x1 += ks0 + 2u;
  TFR4(13,15,26,6)  x0 += ks0; x1 += ks1 + 3u;
  TFR4(17,29,16,24) x0 += ks1; x1 += ks2 + 4u;
  TFR4(13,15,26,6)  x0 += ks2; x1 += ks0 + 5u;
#undef TFR4
  uint32_t bits = x0 ^ x1;
  float u = __uint_as_float((bits >> 9) | 0x3F800000u) - 1.0f;
  u = fminf(fmaxf(u, 1.1920929e-07f), __uint_as_float(0x3F7FFFFEu));
  return -logf(-logf(u));
}

// Kernel 1: grid 4096 = m(4) x rowtile(64) x ktile(16); block 512 thr,
// 32 rows x 256 k. XOR-swizzled codebook LDS (conflict-free b128 reads),
// c2 via shuffle-tree at staging, wave-butterfly argmax reduction (kg spans
// exactly one wave), zero-fill placed before the gumbel loop to drain under
// its ~45us of VALU.
__global__ __launch_bounds__(512) void k_logits(
    const float* __restrict__ x, const float* __restrict__ cb,
    const float* __restrict__ temp, float* __restrict__ logit_out,
    float* __restrict__ sample, float* __restrict__ onehot){
  __shared__ float xl[32][36];     // 32 rows x 32 d (pad 36; reads are broadcast)
  __shared__ float cl[8192];       // 256 k x 32 d, stride 32, float4-slot XOR swizzle
  __shared__ float c2l[256];
  __shared__ float x2l[32];

  const int tid = threadIdx.x;
  const int b = blockIdx.x;
  const int kt = b & 15;           // k-tile 0..15
  const int rt = (b >> 4) & 63;    // row-tile 0..63 (within m)
  const int m  = b >> 10;          // 0..3
  const int n  = rt >> 3;
  const int hw0 = (rt & 7) << 5;
  const int k0 = kt << 8;
  const int rowbase = ((n << 2) + m) * 256 + hw0;

  // ---- stage x tile (32 rows x 32 d) ----
  const float* xm = x + ((n * 128 + m * 32) * 256 + hw0);
  #pragma unroll
  for (int i = 0; i < 2; ++i){
    int idx = tid + (i << 9);
    int d = idx >> 5, r = idx & 31;
    xl[r][d] = xm[(d << 8) + r];
  }
  // ---- stage codebook tile (256 k x 32 d): swizzled store + shuffle-tree c2 ----
  // slot = dq ^ (kk&7): each 8-lane group covers all 32 banks once (no conflict,
  // write side and read side). c2 partial = dot(v,v) reduced over the 8 lanes
  // holding row kk (dq=0..7) — replaces 8192 conflicted LDS reads + a barrier.
  const float4* cb4 = (const float4*)(cb + (m * 131072 + k0 * 32));
  #pragma unroll
  for (int i = 0; i < 4; ++i){
    int f = tid + (i << 9);
    float4 v = cb4[f];
    int kk = f >> 3, dq = f & 7;
    *(float4*)&cl[(kk << 5) + ((dq ^ (kk & 7)) << 2)] = v;
    float p = fmaf(v.x, v.x, fmaf(v.y, v.y, fmaf(v.z, v.z, v.w * v.w)));
    p += __shfl_xor(p, 1);
    p += __shfl_xor(p, 2);
    p += __shfl_xor(p, 4);
    if (dq == 0) c2l[kk] = p;
  }
  __syncthreads();                 // xl, cl, c2l complete

  if (tid < 32){
    float s = 0.f;
    #pragma unroll
    for (int d = 0; d < 32; ++d){ float v = xl[tid][d]; s = fmaf(v, v, s); }
    x2l[tid] = s;                  // visible to all after the post-GEMM barrier
  }

  // ---- GEMM: each thread 4 rows x 4 ks (ks = kg + 64j) ----
  const int kg = tid & 63;         // k-group = lane
  const int rg = tid >> 6;         // wave-uniform row group
  const int sw = kg & 7;           // read-side XOR swizzle
  float acc[4][4];
  #pragma unroll
  for (int i = 0; i < 4; ++i)
    #pragma unroll
    for (int j = 0; j < 4; ++j) acc[i][j] = 0.f;

  #pragma unroll
  for (int dblk = 0; dblk < 8; ++dblk){
    float4 xa[4];
    #pragma unroll
    for (int i = 0; i < 4; ++i)
      xa[i] = *(const float4*)&xl[(rg << 2) + i][dblk << 2];
    #pragma unroll
    for (int j = 0; j < 4; ++j){
      float4 cv = *(const float4*)&cl[((kg + (j << 6)) << 5) + ((dblk ^ sw) << 2)];
      #pragma unroll
      for (int i = 0; i < 4; ++i){
        acc[i][j] = fmaf(xa[i].x, cv.x, acc[i][j]);
        acc[i][j] = fmaf(xa[i].y, cv.y, acc[i][j]);
        acc[i][j] = fmaf(xa[i].z, cv.z, acc[i][j]);
        acc[i][j] = fmaf(xa[i].w, cv.w, acc[i][j]);
      }
    }
  }

  // ---- zero-fill this block's disjoint sample/onehot slice NOW: the stores
  // drain under the gumbel loop's ~45us of pure VALU (fire-and-forget) ----
  {
    const float4 z4 = make_float4(0.f, 0.f, 0.f, 0.f);
    #pragma unroll
    for (int i2 = 0; i2 < 4; ++i2){
      int s = tid + (i2 << 9);          // 2048 float4 slots: 32 rows x 64
      int r = s >> 6, w4 = s & 63;
      size_t f4 = (((size_t)(rowbase + r)) << 10) + (k0 >> 2) + w4;
      ((float4*)onehot)[f4] = z4;
      if (!(kt == 0 && w4 < 16))        // keep sample[row][0:64] = partials area
        ((float4*)sample)[f4] = z4;
    }
  }

  __syncthreads();                 // x2l visible (cl/c2l reads already done pre-GEMM? c2l read below — written pre-first-barrier, still valid)

  // ---- logits + gumbel + per-thread argmax (k ascending -> first-occurrence) ----
  const float tcl = fmaxf(temp[m], 1e-6f);
  float bl[4], bg[4]; int bli[4], bgi[4];
  #pragma unroll
  for (int i = 0; i < 4; ++i){ bl[i] = -INFINITY; bg[i] = -INFINITY; bli[i] = 0; bgi[i] = 0; }

  #pragma unroll
  for (int j = 0; j < 4; ++j){
    const int kk = kg + (j << 6);
    const int k_g = k0 + kk;
    const float c2 = c2l[kk];
    #pragma unroll
    for (int i = 0; i < 4; ++i){
      const int r = (rg << 2) + i;
      const int row_g = rowbase + r;
      float dist = x2l[r] + c2 - 2.0f * acc[i][j];
      float l = (-dist) * 0.015625f * tcl;          // (-dist/64)*t, /64 exact
      logit_out[((size_t)row_g << 12) + k_g] = l;
      float lg = l + gumbel_from_e(((uint32_t)row_g << 12) + (uint32_t)k_g);
      if (l  > bl[i]) { bl[i] = l;  bli[i] = k_g; }
      if (lg > bg[i]) { bg[i] = lg; bgi[i] = k_g; }
    }
  }

  // ---- argmax reduction: kg spans exactly this wave's 64 lanes -> pure
  // intra-wave butterfly (index-carrying, min-index tiebreak). No LDS, no
  // barrier, all 8 waves reduce their own 4 rows in parallel. ----
  #pragma unroll
  for (int i = 0; i < 4; ++i){
    float v = bl[i]; int ix = bli[i];
    float vg = bg[i]; int ixg = bgi[i];
    #pragma unroll
    for (int off = 1; off < 64; off <<= 1){
      float ov = __shfl_xor(v,  off); int oi  = __shfl_xor(ix,  off);
      if (ov > v  || (ov == v  && oi  < ix )){ v  = ov; ix  = oi; }
      float og = __shfl_xor(vg, off); int oig = __shfl_xor(ixg, off);
      if (og > vg || (og == vg && oig < ixg)){ vg = og; ixg = oig; }
    }
    bl[i] = v; bli[i] = ix; bg[i] = vg; bgi[i] = ixg;
  }
  if (kg == 0){                    // all lanes converged; lane 0 of each wave writes
    #pragma unroll
    for (int i = 0; i < 4; ++i){
      float* p = sample + ((size_t)(rowbase + (rg << 2) + i) << 12);
      p[kt]      = bl[i];
      p[16 + kt] = __int_as_float(bli[i]);
      p[32 + kt] = bg[i];
      p[48 + kt] = __int_as_float(bgi[i]);
    }
  }
}

// Kernel 2: one wave per row (2048 blocks x 256 = 4 rows/block). Shuffle-reduce
// the 16 partials, zero sample[row][0:64], scatter the two 1.0s + code.
__global__ __launch_bounds__(256) void k_finalize(
    float* __restrict__ sample, float* __restrict__ code_out,
    float* __restrict__ onehot){
  const int tid = threadIdx.x;
  const int row = (blockIdx.x << 2) + (tid >> 6);
  const int lane = tid & 63;
  float* srow = sample + ((size_t)row << 12);
  float* orow = onehot + ((size_t)row << 12);

  // lanes 0-15 reduce L (logit argmax), lanes 16-31 reduce G (logit+gumbel)
  const int g = (lane >> 4) & 1;
  const int l16 = lane & 15;
  float v; int ix;
  if (lane < 32){
    v  = srow[g * 32 + l16];
    ix = __float_as_int(srow[g * 32 + 16 + l16]);
  } else { v = -INFINITY; ix = 0x7fffffff; }
  #pragma unroll
  for (int off = 1; off < 16; off <<= 1){
    float ov = __shfl_xor(v, off, 16);
    int   oi = __shfl_xor(ix, off, 16);
    if (ov > v || (ov == v && oi < ix)){ v = ov; ix = oi; }
  }
  const int codei = __shfl(ix, 0, 64);   // L winner
  const int hard  = __shfl(ix, 16, 64);  // G winner

  // zero sample[row][0:64]; owner lane embeds the 1.0 if hard < 64 (no race)
  if (lane < 16){
    float4 vs = make_float4(0.f, 0.f, 0.f, 0.f);
    if ((hard >> 2) == lane) ((float*)&vs)[hard & 3] = 1.0f;
    ((float4*)srow)[lane] = vs;
  } else if (lane == 16){
    if (hard >= 64) srow[hard] = 1.0f;   // region already zeroed by K1
  } else if (lane == 17){
    orow[codei] = 1.0f;                  // one_hot(argmax(logit)); zeroed by K1
  } else if (lane == 18){
    code_out[row] = (float)codei;
  }
}

extern "C" void kernel_launch(void* const* d_in, const int* in_sizes, int n_in,
                              void* d_out, int out_size, void* d_ws, size_t ws_size,
                              hipStream_t stream) {
  const float* x    = (const float*)d_in[0];
  const float* cb   = (const float*)d_in[1];
  const float* temp = (const float*)d_in[2];
  float* out    = (float*)d_out;
  float* sample = out;                       // 33554432
  float* code   = out + 33554432;            // 8192
  float* onehot = code + 8192;               // 33554432
  float* logit  = onehot + 33554432;         // 33554432

  hipLaunchKernelGGL(k_logits, dim3(4096), dim3(512), 0, stream,
                     x, cb, temp, logit, sample, onehot);
  hipLaunchKernelGGL(k_finalize, dim3(2048), dim3(256), 0, stream,
                     sample, code, onehot);
}

// Round 8
// 184.216 us; speedup vs baseline: 1.6731x; 1.6731x over previous
//
#include <hip/hip_runtime.h>
#include <stdint.h>

// x: (8,128,16,16) f32 ; codebook: (4,4096,32) f32 ; temperature: (4,1,1,1)
// row = (n*4+m)*256 + hw, 8192 rows, K=4096, D=32
// outputs (flat f32): sample[33554432] code[8192] one_hot[33554432] logit[33554432]

__device__ __forceinline__ uint32_t rotl32(uint32_t x, uint32_t r){
  return (x << r) | (x >> (32u - r));
}

// JAX threefry2x32, key (0,42), partitionable scheme: bits = o0^o1 of
// threefry((0,42),(0,e)); u = bitcast((bits>>9)|0x3F800000)-1, clip, g=-log(-log(u)).
// VALIDATED bit-exact vs reference (Rounds 2,4,6,7) — do not modify.
__device__ __forceinline__ float gumbel_from_e(uint32_t e){
  uint32_t x0 = 0u, x1 = e;
  const uint32_t ks0 = 0u, ks1 = 42u, ks2 = 0x1BD11BF0u;
  x0 += ks0; x1 += ks1;
#define TFR4(a,b,c,d2) \
  x0 += x1; x1 = rotl32(x1,(a)); x1 ^= x0; \
  x0 += x1; x1 = rotl32(x1,(b)); x1 ^= x0; \
  x0 += x1; x1 = rotl32(x1,(c)); x1 ^= x0; \
  x0 += x1; x1 = rotl32(x1,(d2)); x1 ^= x0;
  TFR4(13,15,26,6)  x0 += ks1; x1 += ks2 + 1u;
  TFR4(17,29,16,24) x0 += ks2; x1 += ks0 + 2u;
  TFR4(13,15,26,6)  x0 += ks0; x1 += ks1 + 3u;
  TFR4(17,29,16,24) x0 += ks1; x1 += ks2 + 4u;
  TFR4(13,15,26,6)  x0 += ks2; x1 += ks0 + 5u;
#undef TFR4
  uint32_t bits = x0 ^ x1;
  float u = __uint_as_float((bits >> 9) | 0x3F800000u) - 1.0f;
  u = fminf(fmaxf(u, 1.1920929e-07f), __uint_as_float(0x3F7FFFFEu));
  return -logf(-logf(u));
}

// Kernel 1: grid 4096 = m(4) x rowtile(64) x ktile(16); block 512 thr,
// 32 rows x 256 k. ONE barrier total. x2 accumulated in-register during GEMM
// (no x2l, no second barrier). c2 via shuffle-tree at staging. Intra-wave
// butterfly argmax. Zero-fill of this block's disjoint output slice at the
// VERY END with no trailing barrier: stores drain under the next queued
// block's compute (the Round-7 regression was a __syncthreads after the fill
// forcing a vmcnt(0) drain mid-kernel — do not reintroduce one).
__global__ __launch_bounds__(512) void k_logits(
    const float* __restrict__ x, const float* __restrict__ cb,
    const float* __restrict__ temp, float* __restrict__ logit_out,
    float* __restrict__ sample, float* __restrict__ onehot){
  __shared__ float xl[32][36];     // 32 rows x 32 d (pad 36; reads are wave-broadcast)
  __shared__ float cl[8192];       // 256 k x 32 d, stride 32, float4-slot XOR swizzle
  __shared__ float c2l[256];

  const int tid = threadIdx.x;
  const int b = blockIdx.x;
  const int kt = b & 15;           // k-tile 0..15
  const int rt = (b >> 4) & 63;    // row-tile 0..63 (within m)
  const int m  = b >> 10;          // 0..3
  const int n  = rt >> 3;
  const int hw0 = (rt & 7) << 5;
  const int k0 = kt << 8;
  const int rowbase = ((n << 2) + m) * 256 + hw0;

  // ---- stage x tile (32 rows x 32 d) ----
  const float* xm = x + ((n * 128 + m * 32) * 256 + hw0);
  #pragma unroll
  for (int i = 0; i < 2; ++i){
    int idx = tid + (i << 9);
    int d = idx >> 5, r = idx & 31;
    xl[r][d] = xm[(d << 8) + r];
  }
  // ---- stage codebook tile (256 k x 32 d): swizzled store + shuffle-tree c2 ----
  const float4* cb4 = (const float4*)(cb + (m * 131072 + k0 * 32));
  #pragma unroll
  for (int i = 0; i < 4; ++i){
    int f = tid + (i << 9);
    float4 v = cb4[f];
    int kk = f >> 3, dq = f & 7;
    *(float4*)&cl[(kk << 5) + ((dq ^ (kk & 7)) << 2)] = v;
    float p = fmaf(v.x, v.x, fmaf(v.y, v.y, fmaf(v.z, v.z, v.w * v.w)));
    p += __shfl_xor(p, 1);
    p += __shfl_xor(p, 2);
    p += __shfl_xor(p, 4);
    if (dq == 0) c2l[kk] = p;
  }
  __syncthreads();                 // xl, cl, c2l complete — the ONLY barrier

  // ---- GEMM: each thread 4 rows x 4 ks (ks = kg + 64j); x2 fused in ----
  const int kg = tid & 63;         // k-group = lane
  const int rg = tid >> 6;         // wave-uniform row group
  const int sw = kg & 7;           // read-side XOR swizzle
  float acc[4][4];
  float x2[4] = {0.f, 0.f, 0.f, 0.f};
  #pragma unroll
  for (int i = 0; i < 4; ++i)
    #pragma unroll
    for (int j = 0; j < 4; ++j) acc[i][j] = 0.f;

  #pragma unroll
  for (int dblk = 0; dblk < 8; ++dblk){
    float4 xa[4];
    #pragma unroll
    for (int i = 0; i < 4; ++i){
      xa[i] = *(const float4*)&xl[(rg << 2) + i][dblk << 2];
      x2[i] = fmaf(xa[i].x, xa[i].x, fmaf(xa[i].y, xa[i].y,
               fmaf(xa[i].z, xa[i].z, fmaf(xa[i].w, xa[i].w, x2[i]))));
    }
    #pragma unroll
    for (int j = 0; j < 4; ++j){
      float4 cv = *(const float4*)&cl[((kg + (j << 6)) << 5) + ((dblk ^ sw) << 2)];
      #pragma unroll
      for (int i = 0; i < 4; ++i){
        acc[i][j] = fmaf(xa[i].x, cv.x, acc[i][j]);
        acc[i][j] = fmaf(xa[i].y, cv.y, acc[i][j]);
        acc[i][j] = fmaf(xa[i].z, cv.z, acc[i][j]);
        acc[i][j] = fmaf(xa[i].w, cv.w, acc[i][j]);
      }
    }
  }

  // ---- logits + gumbel + per-thread argmax (k ascending -> first-occurrence) ----
  const float tcl = fmaxf(temp[m], 1e-6f);
  float bl[4], bg[4]; int bli[4], bgi[4];
  #pragma unroll
  for (int i = 0; i < 4; ++i){ bl[i] = -INFINITY; bg[i] = -INFINITY; bli[i] = 0; bgi[i] = 0; }

  #pragma unroll
  for (int j = 0; j < 4; ++j){
    const int kk = kg + (j << 6);
    const int k_g = k0 + kk;
    const float c2 = c2l[kk];
    #pragma unroll
    for (int i = 0; i < 4; ++i){
      const int r = (rg << 2) + i;
      const int row_g = rowbase + r;
      float dist = x2[i] + c2 - 2.0f * acc[i][j];
      float l = (-dist) * 0.015625f * tcl;          // (-dist/64)*t, /64 exact
      logit_out[((size_t)row_g << 12) + k_g] = l;
      float lg = l + gumbel_from_e(((uint32_t)row_g << 12) + (uint32_t)k_g);
      if (l  > bl[i]) { bl[i] = l;  bli[i] = k_g; }
      if (lg > bg[i]) { bg[i] = lg; bgi[i] = k_g; }
    }
  }

  // ---- argmax reduction: kg spans exactly this wave's 64 lanes -> pure
  // intra-wave butterfly (index-carrying, min-index tiebreak). ----
  #pragma unroll
  for (int i = 0; i < 4; ++i){
    float v = bl[i]; int ix = bli[i];
    float vg = bg[i]; int ixg = bgi[i];
    #pragma unroll
    for (int off = 1; off < 64; off <<= 1){
      float ov = __shfl_xor(v,  off); int oi  = __shfl_xor(ix,  off);
      if (ov > v  || (ov == v  && oi  < ix )){ v  = ov; ix  = oi; }
      float og = __shfl_xor(vg, off); int oig = __shfl_xor(ixg, off);
      if (og > vg || (og == vg && oig < ixg)){ vg = og; ixg = oig; }
    }
    bl[i] = v; bli[i] = ix; bg[i] = vg; bgi[i] = ixg;
  }
  if (kg == 0){                    // lane 0 of each wave writes its 4 rows' partials
    #pragma unroll
    for (int i = 0; i < 4; ++i){
      float* p = sample + ((size_t)(rowbase + (rg << 2) + i) << 12);
      p[kt]      = bl[i];
      p[16 + kt] = __int_as_float(bli[i]);
      p[32 + kt] = bg[i];
      p[48 + kt] = __int_as_float(bgi[i]);
    }
  }

  // ---- zero-fill this block's disjoint slice LAST (fire-and-forget; no
  // barrier follows, so stores drain under the next block's compute) ----
  const float4 z4 = make_float4(0.f, 0.f, 0.f, 0.f);
  #pragma unroll
  for (int i2 = 0; i2 < 4; ++i2){
    int s = tid + (i2 << 9);            // 2048 float4 slots: 32 rows x 64
    int r = s >> 6, w4 = s & 63;
    size_t f4 = (((size_t)(rowbase + r)) << 10) + (k0 >> 2) + w4;
    ((float4*)onehot)[f4] = z4;
    if (!(kt == 0 && w4 < 16))          // keep sample[row][0:64] = partials area
      ((float4*)sample)[f4] = z4;
  }
}

// Kernel 2: one wave per row (2048 blocks x 256 = 4 rows/block). Shuffle-reduce
// the 16 partials, zero sample[row][0:64], scatter the two 1.0s + code.
__global__ __launch_bounds__(256) void k_finalize(
    float* __restrict__ sample, float* __restrict__ code_out,
    float* __restrict__ onehot){
  const int tid = threadIdx.x;
  const int row = (blockIdx.x << 2) + (tid >> 6);
  const int lane = tid & 63;
  float* srow = sample + ((size_t)row << 12);
  float* orow = onehot + ((size_t)row << 12);

  // lanes 0-15 reduce L (logit argmax), lanes 16-31 reduce G (logit+gumbel)
  const int g = (lane >> 4) & 1;
  const int l16 = lane & 15;
  float v; int ix;
  if (lane < 32){
    v  = srow[g * 32 + l16];
    ix = __float_as_int(srow[g * 32 + 16 + l16]);
  } else { v = -INFINITY; ix = 0x7fffffff; }
  #pragma unroll
  for (int off = 1; off < 16; off <<= 1){
    float ov = __shfl_xor(v, off, 16);
    int   oi = __shfl_xor(ix, off, 16);
    if (ov > v || (ov == v && oi < ix)){ v = ov; ix = oi; }
  }
  const int codei = __shfl(ix, 0, 64);   // L winner
  const int hard  = __shfl(ix, 16, 64);  // G winner

  // zero sample[row][0:64]; owner lane embeds the 1.0 if hard < 64 (no race)
  if (lane < 16){
    float4 vs = make_float4(0.f, 0.f, 0.f, 0.f);
    if ((hard >> 2) == lane) ((float*)&vs)[hard & 3] = 1.0f;
    ((float4*)srow)[lane] = vs;
  } else if (lane == 16){
    if (hard >= 64) srow[hard] = 1.0f;   // region already zeroed by K1
  } else if (lane == 17){
    orow[codei] = 1.0f;                  // one_hot(argmax(logit)); zeroed by K1
  } else if (lane == 18){
    code_out[row] = (float)codei;
  }
}

extern "C" void kernel_launch(void* const* d_in, const int* in_sizes, int n_in,
                              void* d_out, int out_size, void* d_ws, size_t ws_size,
                              hipStream_t stream) {
  const float* x    = (const float*)d_in[0];
  const float* cb   = (const float*)d_in[1];
  const float* temp = (const float*)d_in[2];
  float* out    = (float*)d_out;
  float* sample = out;                       // 33554432
  float* code   = out + 33554432;            // 8192
  float* onehot = code + 8192;               // 33554432
  float* logit  = onehot + 33554432;         // 33554432

  hipLaunchKernelGGL(k_logits, dim3(4096), dim3(512), 0, stream,
                     x, cb, temp, logit, sample, onehot);
  hipLaunchKernelGGL(k_finalize, dim3(2048), dim3(256), 0, stream,
                     sample, code, onehot);
}